// Round 2
// baseline (6027.058 us; speedup 1.0000x reference)
//
#include <hip/hip_runtime.h>

// SOM BMU one-hot. argmin_k ( ||w_k||^2 - 2 x.w_k ), one-hot over K=1024.
//
// R2 structure:
//   pass1 (fp32): block = 256 thr = 4 waves; each wave = same 64 samples,
//     distinct 256-wide K chunk. x row in 128 VGPRs, w via wave-uniform
//     scalar loads, wsq in LDS. Tracks best AND second-best; samples with
//     gap < MARGIN are appended to a flagged list (expected ~0.4%).
//     Block writes its 64 one-hot rows directly (replaces global memset).
//   pass2 (fp64): one wave per flagged sample, K split 16/lane, shuffle
//     argmin reduce, row rewritten. fp32-vs-fp64 score discrepancy <= ~3e-4,
//     MARGIN = 0.05 -> 150x safety; R1 proved fp64 argmin == reference.

#define SOM_K 1024
#define SOM_D 128
#define P1_BLOCK 256
#define P1_SAMPLES 64      // samples per block (one per lane)
#define P1_KCHUNK 256      // K / 4 waves
#define MARGIN 0.05f
#define FLAG_CAP 32768     // ws: [int counter][pad][int flags...]

__global__ __launch_bounds__(P1_BLOCK, 3) void som_pass1(
    const float* __restrict__ x,
    const float* __restrict__ w,
    float* __restrict__ out,
    int* __restrict__ flag_count,
    int* __restrict__ flag_list,
    int n_samples)
{
    __shared__ float wsq[SOM_K];            // 4 KB
    __shared__ float red_best[4][P1_SAMPLES];
    __shared__ float red_sec[4][P1_SAMPLES];
    __shared__ int   red_k[4][P1_SAMPLES];
    __shared__ int   bmu_s[P1_SAMPLES];

    const int t    = threadIdx.x;
    const int lane = t & 63;
    const int wv   = t >> 6;

    // cooperative ||w_k||^2 (fp32; err ~1e-5, far under MARGIN)
    for (int k = t; k < SOM_K; k += P1_BLOCK) {
        const float* wk = w + k * SOM_D;
        float s0 = 0.f, s1 = 0.f, s2 = 0.f, s3 = 0.f;
        #pragma unroll
        for (int d = 0; d < SOM_D; d += 4) {
            s0 += wk[d + 0] * wk[d + 0];
            s1 += wk[d + 1] * wk[d + 1];
            s2 += wk[d + 2] * wk[d + 2];
            s3 += wk[d + 3] * wk[d + 3];
        }
        wsq[k] = (s0 + s1) + (s2 + s3);
    }

    const int row  = blockIdx.x * P1_SAMPLES + lane;
    const int rowc = (row < n_samples) ? row : (n_samples - 1);

    float xr[SOM_D];
    {
        const float4* xp = (const float4*)(x + (size_t)rowc * SOM_D);
        #pragma unroll
        for (int i = 0; i < SOM_D / 4; ++i) {
            float4 v = xp[i];
            xr[4 * i + 0] = v.x; xr[4 * i + 1] = v.y;
            xr[4 * i + 2] = v.z; xr[4 * i + 3] = v.w;
        }
    }

    __syncthreads();

    float best = 1e30f, second = 1e30f;
    int bk = 0;
    const int k0 = wv * P1_KCHUNK;

    #pragma unroll 1
    for (int kk = 0; kk < P1_KCHUNK; ++kk) {
        const int k = k0 + kk;
        const float* wk = w + k * SOM_D;   // wave-uniform -> scalar loads
        float d0 = 0.f, d1 = 0.f, d2 = 0.f, d3 = 0.f;
        #pragma unroll
        for (int d = 0; d < SOM_D; d += 4) {
            d0 += xr[d + 0] * wk[d + 0];
            d1 += xr[d + 1] * wk[d + 1];
            d2 += xr[d + 2] * wk[d + 2];
            d3 += xr[d + 3] * wk[d + 3];
        }
        float s = wsq[k] - 2.f * ((d0 + d1) + (d2 + d3));
        if (s < best) { second = best; best = s; bk = k; }
        else if (s < second) { second = s; }
    }

    red_best[wv][lane] = best;
    red_sec[wv][lane]  = second;
    red_k[wv][lane]    = bk;
    __syncthreads();

    if (wv == 0) {
        // reduce 4 chunk candidates for sample `lane`; chunks in ascending-k
        // order + strict < == first-min (np.argmin tie-break)
        float gb = 1e30f, gs = 1e30f; int gk = 0;
        #pragma unroll
        for (int c = 0; c < 4; ++c) {
            float b = red_best[c][lane], se = red_sec[c][lane];
            int   kk2 = red_k[c][lane];
            if (b < gb) { gs = fminf(gb, se); gb = b; gk = kk2; }
            else        { gs = fminf(gs, b); }
        }
        bmu_s[lane] = gk;
        if (row < n_samples && (gs - gb) < MARGIN) {
            int idx = atomicAdd(flag_count, 1);
            if (idx < FLAG_CAP) flag_list[idx] = row;
        }
    }
    __syncthreads();

    // cooperative one-hot write: wave wv handles rows wv, wv+4, ...
    for (int r = wv; r < P1_SAMPLES; r += 4) {
        const int row2 = blockIdx.x * P1_SAMPLES + r;
        if (row2 >= n_samples) continue;
        const int bmu = bmu_s[r];
        float4* op = (float4*)(out + (size_t)row2 * SOM_K);
        #pragma unroll
        for (int j = lane; j < SOM_K / 4; j += 64) {
            float4 v = {0.f, 0.f, 0.f, 0.f};
            const int base = j * 4;
            if (bmu >= base && bmu < base + 4) ((float*)&v)[bmu - base] = 1.0f;
            op[j] = v;
        }
    }
}

__global__ __launch_bounds__(64) void som_pass2(
    const float* __restrict__ x,
    const float* __restrict__ w,
    float* __restrict__ out,
    const int* __restrict__ flag_count,
    const int* __restrict__ flag_list)
{
    __shared__ float xs[SOM_D];
    const int t = threadIdx.x;
    int cnt = *flag_count;
    if (cnt > FLAG_CAP) cnt = FLAG_CAP;

    for (int i = blockIdx.x; i < cnt; i += gridDim.x) {
        const int row = flag_list[i];
        xs[t]      = x[(size_t)row * SOM_D + t];
        xs[t + 64] = x[(size_t)row * SOM_D + t + 64];
        __syncthreads();

        double best = 1.0e300;
        int bk = 0;
        // lane t owns k in [t*16, t*16+16) -> ascending k across lanes
        #pragma unroll 1
        for (int kk = 0; kk < 16; ++kk) {
            const int k = t * 16 + kk;
            const float* wk = w + k * SOM_D;
            double s0 = 0.0, s1 = 0.0;
            #pragma unroll
            for (int d = 0; d < SOM_D; d += 2) {
                double w0 = (double)wk[d],     x0 = (double)xs[d];
                double w1 = (double)wk[d + 1], x1 = (double)xs[d + 1];
                s0 += w0 * (w0 - 2.0 * x0);
                s1 += w1 * (w1 - 2.0 * x1);
            }
            double s = s0 + s1;
            if (s < best) { best = s; bk = k; }
        }
        // wave argmin reduce, tie -> smaller k (first-min)
        #pragma unroll
        for (int off = 32; off > 0; off >>= 1) {
            double ob  = __shfl_down(best, off);
            int    obk = __shfl_down(bk, off);
            if (ob < best || (ob == best && obk < bk)) { best = ob; bk = obk; }
        }
        bk = __shfl(bk, 0);

        // rewrite the row: zero all 1024, then set bk
        float4* op = (float4*)(out + (size_t)row * SOM_K);
        const float4 z = {0.f, 0.f, 0.f, 0.f};
        #pragma unroll
        for (int j = t; j < SOM_K / 4; j += 64) op[j] = z;
        __syncthreads();   // also guards xs reuse next iteration
        if (t == 0) out[(size_t)row * SOM_K + bk] = 1.0f;
        __syncthreads();
    }
}

extern "C" void kernel_launch(void* const* d_in, const int* in_sizes, int n_in,
                              void* d_out, int out_size, void* d_ws, size_t ws_size,
                              hipStream_t stream) {
    const float* x = (const float*)d_in[0];
    const float* w = (const float*)d_in[1];
    float* out = (float*)d_out;

    const int n_samples = in_sizes[0] / SOM_D;  // 100000

    int* flag_count = (int*)d_ws;
    int* flag_list  = (int*)d_ws + 4;  // 16-byte offset

    hipMemsetAsync(d_ws, 0, 16, stream);  // zero the flag counter

    const int grid1 = (n_samples + P1_SAMPLES - 1) / P1_SAMPLES;  // 1563
    som_pass1<<<grid1, P1_BLOCK, 0, stream>>>(x, w, out, flag_count, flag_list,
                                              n_samples);
    som_pass2<<<1024, 64, 0, stream>>>(x, w, out, flag_count, flag_list);
}

// Round 3
// 909.101 us; speedup vs baseline: 6.6297x; 6.6297x over previous
//
#include <hip/hip_runtime.h>

// SOM BMU one-hot via split-bf16 MFMA GEMM.
//   score_k = ||w_k||^2 - 2 * x.w_k ; bmu = argmin_k ; out = one_hot[N=100000][K=1024]
//
// R3: pass1 = MFMA (16x16x32 bf16). x,w split hi/lo bf16; dot = xh*wh + xh*wl
// + xl*wh (inner dim 384; dropped xl*wl ~2^-18 rel). Score err < ~5e-3,
// MARGIN=0.08 -> flag rate <1%; flagged rows re-solved exactly in fp64 pass2
// (R1 proved fp64 argmin == np reference on all 100k rows).
//
// R2 post-mortem: 128-float per-thread array spilled (VGPR_Count=84, FETCH
// 7.4GB). R3 holds x as 16 MFMA a-frags (64 VGPRs) converted ONCE -- no per-k
// x traffic, no spill surface.

typedef __attribute__((ext_vector_type(8))) short bf16x8;   // 8 bf16 = 4 VGPR
typedef __attribute__((ext_vector_type(4))) float f32x4;

#define SOM_K 1024
#define SOM_D 128
#define MARGIN 0.08f
#define FLAG_CAP 32768

// d_ws layout (bytes):
//   [0]       flag_count (int)
//   [64]      wsq   : 1024 f32                     (4 KB)
//   [8192]    w2    : 1024 x 384 bf16 = [wh|wl|wh] (768 KB)
//   [794624]  flag_list : 32768 int                (128 KB)
#define WS_WSQ   64
#define WS_W2    8192
#define WS_FLAGS 794624

static __device__ __forceinline__ unsigned short f2bf(float f) {
    unsigned u = __float_as_uint(f);
    unsigned r = (u + 0x7FFFu + ((u >> 16) & 1u)) >> 16;   // RNE
    return (unsigned short)r;
}
static __device__ __forceinline__ float bf2f(unsigned short h) {
    return __uint_as_float(((unsigned)h) << 16);
}

// ---- prep: w -> w2 (split bf16, [wh|wl|wh]) + exact wsq -------------------
__global__ __launch_bounds__(64) void som_prep(
    const float* __restrict__ w, unsigned short* __restrict__ w2,
    float* __restrict__ wsq)
{
    const int n = blockIdx.x;          // proto 0..1023
    const int d = threadIdx.x;
    float v0 = w[n * SOM_D + d];
    float v1 = w[n * SOM_D + 64 + d];
    unsigned short h0 = f2bf(v0), h1 = f2bf(v1);
    unsigned short l0 = f2bf(v0 - bf2f(h0)), l1 = f2bf(v1 - bf2f(h1));
    unsigned short* r = w2 + n * 384;
    r[d] = h0;       r[64 + d] = h1;        // wh
    r[128 + d] = l0; r[192 + d] = l1;       // wl
    r[256 + d] = h0; r[320 + d] = h1;       // wh again (pairs with xl)
    double s = (double)v0 * v0 + (double)v1 * v1;
    #pragma unroll
    for (int off = 32; off > 0; off >>= 1) s += __shfl_down(s, off);
    if (d == 0) wsq[n] = (float)s;
}

// ---- pass1: MFMA GEMM + argmin + one-hot write ----------------------------
__global__ __launch_bounds__(64, 2) void som_main(
    const float* __restrict__ x,
    const unsigned short* __restrict__ w2,
    const float* __restrict__ wsq,
    float* __restrict__ out,
    int* __restrict__ flag_count,
    int* __restrict__ flag_list)
{
    __shared__ int bmu_s[32];
    const int lane = threadIdx.x;            // one wave per block
    const int c = lane & 15;                 // col within 16-tile
    const int q = lane >> 4;                 // quad 0..3
    const int R0 = blockIdx.x * 32;          // 3125 blocks * 32 = 100000 exact

    // a-frags: A[m=lane&15][k=8q+j], two 16-row groups, hi+lo. 16 frags.
    bf16x8 ah[2][4], al[2][4];
    #pragma unroll
    for (int g = 0; g < 2; ++g) {
        const float* xp = x + (size_t)(R0 + 16 * g + c) * SOM_D + 8 * q;
        #pragma unroll
        for (int s = 0; s < 4; ++s) {
            float4 v0 = *(const float4*)(xp + 32 * s);
            float4 v1 = *(const float4*)(xp + 32 * s + 4);
            float xv[8] = {v0.x, v0.y, v0.z, v0.w, v1.x, v1.y, v1.z, v1.w};
            bf16x8 hh, ll;
            #pragma unroll
            for (int j = 0; j < 8; ++j) {
                unsigned short h = f2bf(xv[j]);
                hh[j] = (short)h;
                ll[j] = (short)f2bf(xv[j] - bf2f(h));
            }
            ah[g][s] = hh; al[g][s] = ll;
        }
    }

    float best[2][4], sec[2][4];
    int bk[2][4];
    #pragma unroll
    for (int g = 0; g < 2; ++g)
        #pragma unroll
        for (int r = 0; r < 4; ++r) { best[g][r] = 1e30f; sec[g][r] = 1e30f; bk[g][r] = 0; }

    #pragma unroll 1
    for (int nt = 0; nt < 64; ++nt) {
        const int n0 = nt * 16;
        // b-frags: B[k=32s+8q+j][n=n0+c]  (w2 row-major [proto][kk])
        const unsigned short* wp = w2 + (size_t)(n0 + c) * 384 + 8 * q;
        bf16x8 b[12];
        #pragma unroll
        for (int s = 0; s < 12; ++s) b[s] = *(const bf16x8*)(wp + 32 * s);
        const float wq = wsq[n0 + c];

        f32x4 a0 = {0.f, 0.f, 0.f, 0.f}, a1 = {0.f, 0.f, 0.f, 0.f};
        #pragma unroll
        for (int s = 0; s < 4; ++s) {   // xh * wh
            a0 = __builtin_amdgcn_mfma_f32_16x16x32_bf16(ah[0][s], b[s], a0, 0, 0, 0);
            a1 = __builtin_amdgcn_mfma_f32_16x16x32_bf16(ah[1][s], b[s], a1, 0, 0, 0);
        }
        #pragma unroll
        for (int s = 0; s < 4; ++s) {   // xh * wl
            a0 = __builtin_amdgcn_mfma_f32_16x16x32_bf16(ah[0][s], b[4 + s], a0, 0, 0, 0);
            a1 = __builtin_amdgcn_mfma_f32_16x16x32_bf16(ah[1][s], b[4 + s], a1, 0, 0, 0);
        }
        #pragma unroll
        for (int s = 0; s < 4; ++s) {   // xl * wh
            a0 = __builtin_amdgcn_mfma_f32_16x16x32_bf16(al[0][s], b[8 + s], a0, 0, 0, 0);
            a1 = __builtin_amdgcn_mfma_f32_16x16x32_bf16(al[1][s], b[8 + s], a1, 0, 0, 0);
        }

        // D layout: row m = 4q + r, col = n0 + c. Track best/second per row.
        #pragma unroll
        for (int r = 0; r < 4; ++r) {
            float s0 = wq - 2.f * a0[r];
            if (s0 < best[0][r]) { sec[0][r] = best[0][r]; best[0][r] = s0; bk[0][r] = n0 + c; }
            else if (s0 < sec[0][r]) sec[0][r] = s0;
            float s1 = wq - 2.f * a1[r];
            if (s1 < best[1][r]) { sec[1][r] = best[1][r]; best[1][r] = s1; bk[1][r] = n0 + c; }
            else if (s1 < sec[1][r]) sec[1][r] = s1;
        }
    }

    // reduce (best, sec, bk) across the 16 lanes of each quad-group
    #pragma unroll
    for (int g = 0; g < 2; ++g) {
        #pragma unroll
        for (int r = 0; r < 4; ++r) {
            float b0 = best[g][r], s0 = sec[g][r];
            int k0 = bk[g][r];
            #pragma unroll
            for (int m = 1; m < 16; m <<= 1) {
                float ob = __shfl_xor(b0, m);
                float os = __shfl_xor(s0, m);
                int   ok = __shfl_xor(k0, m);
                if (ob < b0 || (ob == b0 && ok < k0)) {
                    s0 = fminf(b0, os); b0 = ob; k0 = ok;
                } else {
                    s0 = fminf(s0, ob);
                }
            }
            best[g][r] = b0; sec[g][r] = s0; bk[g][r] = k0;
        }
    }

    if (c == 0) {   // lanes 0,16,32,48: rows 4q..4q+3 of each group
        #pragma unroll
        for (int g = 0; g < 2; ++g) {
            #pragma unroll
            for (int r = 0; r < 4; ++r) {
                const int idx = g * 16 + 4 * q + r;
                bmu_s[idx] = bk[g][r];
                if (sec[g][r] - best[g][r] < MARGIN) {
                    int i = atomicAdd(flag_count, 1);
                    if (i < FLAG_CAP) flag_list[i] = R0 + idx;
                }
            }
        }
    }
    __syncthreads();

    // one-hot write: one full row (4 KB) per iteration, coalesced float4
    #pragma unroll 1
    for (int rr = 0; rr < 32; ++rr) {
        const int bmu = bmu_s[rr];
        float4* op = (float4*)(out + (size_t)(R0 + rr) * SOM_K);
        #pragma unroll
        for (int j = 0; j < 4; ++j) {
            const int e = j * 64 + lane;          // float4 index 0..255
            float4 v = {0.f, 0.f, 0.f, 0.f};
            if ((bmu >> 2) == e) ((float*)&v)[bmu & 3] = 1.0f;
            op[e] = v;
        }
    }
}

// ---- pass2: exact fp64 re-solve of flagged rows (verbatim from R2, passed) -
__global__ __launch_bounds__(64) void som_pass2(
    const float* __restrict__ x,
    const float* __restrict__ w,
    float* __restrict__ out,
    const int* __restrict__ flag_count,
    const int* __restrict__ flag_list)
{
    __shared__ float xs[SOM_D];
    const int t = threadIdx.x;
    int cnt = *flag_count;
    if (cnt > FLAG_CAP) cnt = FLAG_CAP;

    for (int i = blockIdx.x; i < cnt; i += gridDim.x) {
        const int row = flag_list[i];
        xs[t]      = x[(size_t)row * SOM_D + t];
        xs[t + 64] = x[(size_t)row * SOM_D + t + 64];
        __syncthreads();

        double best = 1.0e300;
        int bk = 0;
        #pragma unroll 1
        for (int kk = 0; kk < 16; ++kk) {
            const int k = t * 16 + kk;
            const float* wk = w + k * SOM_D;
            double s0 = 0.0, s1 = 0.0;
            #pragma unroll
            for (int d = 0; d < SOM_D; d += 2) {
                double w0 = (double)wk[d],     x0 = (double)xs[d];
                double w1 = (double)wk[d + 1], x1 = (double)xs[d + 1];
                s0 += w0 * (w0 - 2.0 * x0);
                s1 += w1 * (w1 - 2.0 * x1);
            }
            double s = s0 + s1;
            if (s < best) { best = s; bk = k; }
        }
        #pragma unroll
        for (int off = 32; off > 0; off >>= 1) {
            double ob  = __shfl_down(best, off);
            int    obk = __shfl_down(bk, off);
            if (ob < best || (ob == best && obk < bk)) { best = ob; bk = obk; }
        }
        bk = __shfl(bk, 0);

        float4* op = (float4*)(out + (size_t)row * SOM_K);
        const float4 z = {0.f, 0.f, 0.f, 0.f};
        #pragma unroll
        for (int j = t; j < SOM_K / 4; j += 64) op[j] = z;
        __syncthreads();
        if (t == 0) out[(size_t)row * SOM_K + bk] = 1.0f;
        __syncthreads();
    }
}

extern "C" void kernel_launch(void* const* d_in, const int* in_sizes, int n_in,
                              void* d_out, int out_size, void* d_ws, size_t ws_size,
                              hipStream_t stream) {
    const float* x = (const float*)d_in[0];
    const float* w = (const float*)d_in[1];
    float* out = (float*)d_out;

    char* ws = (char*)d_ws;
    int*            flag_count = (int*)ws;
    float*          wsq        = (float*)(ws + WS_WSQ);
    unsigned short* w2         = (unsigned short*)(ws + WS_W2);
    int*            flag_list  = (int*)(ws + WS_FLAGS);

    hipMemsetAsync(d_ws, 0, 64, stream);   // flag counter

    som_prep<<<SOM_K, 64, 0, stream>>>(w, w2, wsq);
    som_main<<<3125, 64, 0, stream>>>(x, w2, wsq, out, flag_count, flag_list);
    som_pass2<<<1024, 64, 0, stream>>>(x, w, out, flag_count, flag_list);
}

// Round 5
// 863.990 us; speedup vs baseline: 6.9758x; 1.0522x over previous
//
#include <hip/hip_runtime.h>

// SOM BMU one-hot via split-bf16 MFMA GEMM. R4 structure:
//   som_prep : w -> w2[1024][384] bf16 ([wh|wl|wh]) + exact wsq
//   som_main : MFMA GEMM, double-buffered B prefetch, emits bmu[N] + flags
//   som_pass2: fp64 re-solve of flagged rows, patches bmu[] only
//   som_write: dedicated streaming one-hot writer (nontemporal f32x4),
//              covers every output element -> no d_out memset needed.
//
// R3 post-mortem: fused kernel was latency-bound (MfmaUtil 7.5%, 81% idle) --
// per-tile serial chain [12 L2 loads -> waitcnt -> MFMA -> argmin] with ~1.5
// waves/SIMD. R4: prefetch hides L2 latency; write split out so it streams.
// R4 fix: __builtin_nontemporal_store needs a clang vector type, not HIP float4.

typedef __attribute__((ext_vector_type(8))) short bf16x8;   // 8 bf16 = 4 VGPR
typedef __attribute__((ext_vector_type(4))) float f32x4;

#define SOM_K 1024
#define SOM_D 128
#define MARGIN 0.08f
#define FLAG_CAP 8192

// d_ws layout (bytes):
#define WS_WSQ   64        // 1024 f32   (4 KB)
#define WS_W2    8192      // 1024x384 bf16 (768 KB)
#define WS_FLAGS 794624    // 8192 int   (32 KB)
#define WS_BMU   827392    // 100000 int (400 KB) -> ends ~1.23 MB

static __device__ __forceinline__ unsigned short f2bf(float f) {
    unsigned u = __float_as_uint(f);
    return (unsigned short)((u + 0x7FFFu + ((u >> 16) & 1u)) >> 16);  // RNE
}
static __device__ __forceinline__ float bf2f(unsigned short h) {
    return __uint_as_float(((unsigned)h) << 16);
}

// ---- prep: w -> w2 (split bf16, [wh|wl|wh]) + exact wsq -------------------
__global__ __launch_bounds__(64) void som_prep(
    const float* __restrict__ w, unsigned short* __restrict__ w2,
    float* __restrict__ wsq)
{
    const int n = blockIdx.x;
    const int d = threadIdx.x;
    float v0 = w[n * SOM_D + d];
    float v1 = w[n * SOM_D + 64 + d];
    unsigned short h0 = f2bf(v0), h1 = f2bf(v1);
    unsigned short l0 = f2bf(v0 - bf2f(h0)), l1 = f2bf(v1 - bf2f(h1));
    unsigned short* r = w2 + n * 384;
    r[d] = h0;       r[64 + d] = h1;
    r[128 + d] = l0; r[192 + d] = l1;
    r[256 + d] = h0; r[320 + d] = h1;
    double s = (double)v0 * v0 + (double)v1 * v1;
    #pragma unroll
    for (int off = 32; off > 0; off >>= 1) s += __shfl_down(s, off);
    if (d == 0) wsq[n] = (float)s;
}

// ---- main: MFMA GEMM + argmin, double-buffered B --------------------------
__global__ __launch_bounds__(64, 2) void som_main(
    const float* __restrict__ x,
    const unsigned short* __restrict__ w2,
    const float* __restrict__ wsq,
    int* __restrict__ bmu_out,
    int* __restrict__ flag_count,
    int* __restrict__ flag_list)
{
    const int lane = threadIdx.x;
    const int c = lane & 15;
    const int q = lane >> 4;
    const int R0 = blockIdx.x * 32;          // 3125 * 32 = 100000 exact

    // a-frags: A[m=lane&15][k=8q+j], two 16-row groups, hi+lo (64 VGPR).
    bf16x8 ah[2][4], al[2][4];
    #pragma unroll
    for (int g = 0; g < 2; ++g) {
        const float* xp = x + (size_t)(R0 + 16 * g + c) * SOM_D + 8 * q;
        #pragma unroll
        for (int s = 0; s < 4; ++s) {
            float4 v0 = *(const float4*)(xp + 32 * s);
            float4 v1 = *(const float4*)(xp + 32 * s + 4);
            float xv[8] = {v0.x, v0.y, v0.z, v0.w, v1.x, v1.y, v1.z, v1.w};
            bf16x8 hh, ll;
            #pragma unroll
            for (int j = 0; j < 8; ++j) {
                unsigned short h = f2bf(xv[j]);
                hh[j] = (short)h;
                ll[j] = (short)f2bf(xv[j] - bf2f(h));
            }
            ah[g][s] = hh; al[g][s] = ll;
        }
    }

    float best[2][4], sec[2][4];
    int bk[2][4];
    #pragma unroll
    for (int g = 0; g < 2; ++g)
        #pragma unroll
        for (int r = 0; r < 4; ++r) { best[g][r] = 1e30f; sec[g][r] = 1e30f; bk[g][r] = 0; }

    const unsigned short* wbase = w2 + (size_t)c * 384 + 8 * q;

    auto compute_tile = [&](int n0, const bf16x8* b, float wq) {
        f32x4 a0 = {0.f, 0.f, 0.f, 0.f}, a1 = {0.f, 0.f, 0.f, 0.f};
        #pragma unroll
        for (int s = 0; s < 4; ++s) {   // xh * wh
            a0 = __builtin_amdgcn_mfma_f32_16x16x32_bf16(ah[0][s], b[s], a0, 0, 0, 0);
            a1 = __builtin_amdgcn_mfma_f32_16x16x32_bf16(ah[1][s], b[s], a1, 0, 0, 0);
        }
        #pragma unroll
        for (int s = 0; s < 4; ++s) {   // xh * wl
            a0 = __builtin_amdgcn_mfma_f32_16x16x32_bf16(ah[0][s], b[4 + s], a0, 0, 0, 0);
            a1 = __builtin_amdgcn_mfma_f32_16x16x32_bf16(ah[1][s], b[4 + s], a1, 0, 0, 0);
        }
        #pragma unroll
        for (int s = 0; s < 4; ++s) {   // xl * wh
            a0 = __builtin_amdgcn_mfma_f32_16x16x32_bf16(al[0][s], b[8 + s], a0, 0, 0, 0);
            a1 = __builtin_amdgcn_mfma_f32_16x16x32_bf16(al[1][s], b[8 + s], a1, 0, 0, 0);
        }
        #pragma unroll
        for (int r = 0; r < 4; ++r) {
            float s0 = wq - 2.f * a0[r];
            if (s0 < best[0][r]) { sec[0][r] = best[0][r]; best[0][r] = s0; bk[0][r] = n0 + c; }
            else if (s0 < sec[0][r]) sec[0][r] = s0;
            float s1 = wq - 2.f * a1[r];
            if (s1 < best[1][r]) { sec[1][r] = best[1][r]; best[1][r] = s1; bk[1][r] = n0 + c; }
            else if (s1 < sec[1][r]) sec[1][r] = s1;
        }
    };

    bf16x8 b0[12], b1[12];
    float wq0, wq1;
    {   // tile 0 -> b0
        #pragma unroll
        for (int s = 0; s < 12; ++s) b0[s] = *(const bf16x8*)(wbase + 32 * s);
        wq0 = wsq[c];
    }

    #pragma unroll 1
    for (int it = 0; it < 32; ++it) {
        const int ntA = 2 * it, ntB = 2 * it + 1;
        {   // prefetch ntB -> b1 (before using b0)
            const unsigned short* wp = wbase + (size_t)ntB * 16 * 384;
            #pragma unroll
            for (int s = 0; s < 12; ++s) b1[s] = *(const bf16x8*)(wp + 32 * s);
            wq1 = wsq[ntB * 16 + c];
        }
        compute_tile(ntA * 16, b0, wq0);
        if (it < 31) {   // prefetch ntA+2 -> b0 (before using b1)
            const unsigned short* wp = wbase + (size_t)(ntA + 2) * 16 * 384;
            #pragma unroll
            for (int s = 0; s < 12; ++s) b0[s] = *(const bf16x8*)(wp + 32 * s);
            wq0 = wsq[(ntA + 2) * 16 + c];
        }
        compute_tile(ntB * 16, b1, wq1);
    }

    // reduce (best, sec, bk) across the 16 c-lanes of each quad-group
    #pragma unroll
    for (int g = 0; g < 2; ++g) {
        #pragma unroll
        for (int r = 0; r < 4; ++r) {
            float b0v = best[g][r], s0v = sec[g][r];
            int k0 = bk[g][r];
            #pragma unroll
            for (int m = 1; m < 16; m <<= 1) {
                float ob = __shfl_xor(b0v, m);
                float os = __shfl_xor(s0v, m);
                int   ok = __shfl_xor(k0, m);
                if (ob < b0v || (ob == b0v && ok < k0)) {
                    s0v = fminf(b0v, os); b0v = ob; k0 = ok;
                } else {
                    s0v = fminf(s0v, ob);
                }
            }
            best[g][r] = b0v; sec[g][r] = s0v; bk[g][r] = k0;
        }
    }

    if (c == 0) {   // lanes 0,16,32,48 hold rows g*16 + 4q + r
        #pragma unroll
        for (int g = 0; g < 2; ++g) {
            #pragma unroll
            for (int r = 0; r < 4; ++r) {
                const int row = R0 + g * 16 + 4 * q + r;
                bmu_out[row] = bk[g][r];
                if (sec[g][r] - best[g][r] < MARGIN) {
                    int i = atomicAdd(flag_count, 1);
                    if (i < FLAG_CAP) flag_list[i] = row;
                }
            }
        }
    }
}

// ---- pass2: exact fp64 re-solve of flagged rows -> patch bmu[] ------------
__global__ __launch_bounds__(64) void som_pass2(
    const float* __restrict__ x,
    const float* __restrict__ w,
    int* __restrict__ bmu_out,
    const int* __restrict__ flag_count,
    const int* __restrict__ flag_list)
{
    __shared__ float xs[SOM_D];
    const int t = threadIdx.x;
    int cnt = *flag_count;
    if (cnt > FLAG_CAP) cnt = FLAG_CAP;

    for (int i = blockIdx.x; i < cnt; i += gridDim.x) {
        const int row = flag_list[i];
        __syncthreads();   // xs reuse guard
        xs[t]      = x[(size_t)row * SOM_D + t];
        xs[t + 64] = x[(size_t)row * SOM_D + t + 64];
        __syncthreads();

        double best = 1.0e300;
        int bk = 0;
        #pragma unroll 1
        for (int kk = 0; kk < 16; ++kk) {
            const int k = t * 16 + kk;
            const float* wk = w + k * SOM_D;
            double s0 = 0.0, s1 = 0.0;
            #pragma unroll
            for (int d = 0; d < SOM_D; d += 2) {
                double w0 = (double)wk[d],     x0 = (double)xs[d];
                double w1 = (double)wk[d + 1], x1 = (double)xs[d + 1];
                s0 += w0 * (w0 - 2.0 * x0);
                s1 += w1 * (w1 - 2.0 * x1);
            }
            double s = s0 + s1;
            if (s < best) { best = s; bk = k; }
        }
        #pragma unroll
        for (int off = 32; off > 0; off >>= 1) {
            double ob  = __shfl_down(best, off);
            int    obk = __shfl_down(bk, off);
            if (ob < best || (ob == best && obk < bk)) { best = ob; bk = obk; }
        }
        if (t == 0) bmu_out[row] = bk;
    }
}

// ---- writer: streaming one-hot, covers every element ----------------------
__global__ __launch_bounds__(256) void som_write(
    float* __restrict__ out, const int* __restrict__ bmu, int n)
{
    const int lane = threadIdx.x & 63;
    const int wv   = threadIdx.x >> 6;
    const int wave_id = blockIdx.x * 4 + wv;
    const int nwaves  = gridDim.x * 4;

    for (int row = wave_id; row < n; row += nwaves) {
        const int b = bmu[row];
        f32x4* op = (f32x4*)(out + (size_t)row * SOM_K);
        #pragma unroll
        for (int j = 0; j < 4; ++j) {
            const int e = j * 64 + lane;
            f32x4 v = {0.f, 0.f, 0.f, 0.f};
            if ((b >> 2) == e) v[b & 3] = 1.0f;
            __builtin_nontemporal_store(v, op + e);
        }
    }
}

extern "C" void kernel_launch(void* const* d_in, const int* in_sizes, int n_in,
                              void* d_out, int out_size, void* d_ws, size_t ws_size,
                              hipStream_t stream) {
    const float* x = (const float*)d_in[0];
    const float* w = (const float*)d_in[1];
    float* out = (float*)d_out;

    const int n_samples = in_sizes[0] / SOM_D;  // 100000

    char* ws = (char*)d_ws;
    int*            flag_count = (int*)ws;
    float*          wsq        = (float*)(ws + WS_WSQ);
    unsigned short* w2         = (unsigned short*)(ws + WS_W2);
    int*            flag_list  = (int*)(ws + WS_FLAGS);
    int*            bmu        = (int*)(ws + WS_BMU);

    (void)hipMemsetAsync(d_ws, 0, 64, stream);   // flag counter

    som_prep<<<SOM_K, 64, 0, stream>>>(w, w2, wsq);
    som_main<<<3125, 64, 0, stream>>>(x, w2, wsq, bmu, flag_count, flag_list);
    som_pass2<<<1024, 64, 0, stream>>>(x, w, bmu, flag_count, flag_list);
    som_write<<<2048, 256, 0, stream>>>(out, bmu, n_samples);
}